// Round 15
// baseline (240.748 us; speedup 1.0000x reference)
//
#include <hip/hip_runtime.h>
#include <hip/hip_bf16.h>
#include <stdint.h>

#define SEQ 4096
#define HID 1152
#define NH  16
#define HD  72
#define N3  3456
#define DQ  80      // Q padded head dim (5 x 16)
#define QBLK 256    // q rows per attn block (8 waves x 32)
#define TILE_ELEMS 14336  // 28KB tile image: K 64x256B = 16KB, V 96x128B = 12KB

typedef __bf16 bf16;
typedef __bf16 bf16x8 __attribute__((ext_vector_type(8)));
typedef float  f32x4  __attribute__((ext_vector_type(4)));
typedef float  f32x16 __attribute__((ext_vector_type(16)));
typedef uint32_t u32x4 __attribute__((ext_vector_type(4)));

#define EXP2F(x) __builtin_amdgcn_exp2f(x)
#define PLSWAP(a, b) asm("v_permlane32_swap_b32 %0, %1" : "+v"(a), "+v"(b))
#define QSCALE (0.11785113019775793f * 1.4426950408889634f)   // 72^-0.5 * log2e

__device__ __forceinline__ void gload_lds16(const void* g, void* l) {
    __builtin_amdgcn_global_load_lds(
        (__attribute__((address_space(1))) void*)(void*)g,
        (__attribute__((address_space(3))) void*)l, 16, 0, 0);
}
__device__ __forceinline__ uint16_t bfbits(float x) {
    return __builtin_bit_cast(uint16_t, (bf16)x);
}

// bijective XCD swizzle (nwg % 8 == 0 where used)
__device__ __forceinline__ int xcd_swz(int orig, int nwg) {
    return (orig & 7) * (nwg >> 3) + (orig >> 3);
}

// ---------------- fused prep: cvt + weight transposes + KVp/Qp pad prefill ----------------
// blocks [0,2304): cvt hidden; [2304,6192): Wqkv^T; [6192,7488): Wproj^T;
// [7488,7744): Qp pad (d 72..79 = 0); [7744,9536): K-image pad (dims 72..127 = 0);
// [9536,10304): V-image pad (d=72 ones for l-via-MFMA, d 73..95 zero).
__global__ __launch_bounds__(256)
void prep(const float* __restrict__ hidden, const float* __restrict__ Wqkv,
          const float* __restrict__ Wproj, bf16* __restrict__ hid_b,
          bf16* __restrict__ WqkvT, bf16* __restrict__ WprojT,
          bf16* __restrict__ Qp, bf16* __restrict__ KVp)
{
    __shared__ float tl[32][33];
    int b = blockIdx.x, tid = threadIdx.x;
    if (b < 2304) {
        int i = b * 256 + tid;
        const float4* p = (const float4*)hidden + (size_t)i * 2;
        float4 a = p[0], c = p[1];
        bf16x8 o;
        o[0]=(bf16)a.x; o[1]=(bf16)a.y; o[2]=(bf16)a.z; o[3]=(bf16)a.w;
        o[4]=(bf16)c.x; o[5]=(bf16)c.y; o[6]=(bf16)c.z; o[7]=(bf16)c.w;
        ((bf16x8*)hid_b)[i] = o;
        return;
    }
    if (b >= 7488) {
        bf16x8 zero = {};
        if (b < 7744) {                  // Qp pad
            int idx = (b - 7488) * 256 + tid;        // 16*4096
            int h = idx >> 12, s = idx & 4095;
            *(bf16x8*)&Qp[((size_t)(h * 4096 + s)) * DQ + 72] = zero;
        } else if (b < 9536) {           // K-image pad: chunks dchunk 9..15
            int flat = (b - 7744) * 256 + tid;       // 65536*7
            int j7 = flat % 7, rest = flat / 7;
            int key = rest & 63, t = (rest >> 6) & 63, h = rest >> 12;
            int pos = key * 16 + ((9 + j7) ^ (key & 15));
            *(bf16x8*)&KVp[((size_t)(h * 64 + t)) * TILE_ELEMS + pos * 8] = zero;
        } else {                         // V-image pad rows 72..95
            int flat = (b - 9536) * 256 + tid;       // 196608
            int j = flat & 7, d = 72 + ((flat >> 3) % 24);
            int t = (flat / 192) & 63, h = flat / 12288;
            bf16x8 v = zero;
            if (d == 72)
#pragma unroll
                for (int e = 0; e < 8; ++e) v[e] = (bf16)1.f;
            *(bf16x8*)&KVp[((size_t)(h * 64 + t)) * TILE_ELEMS + 8192 + d * 64 + j * 8] = v;
        }
        return;
    }
    const float* in; bf16* out; int R, C, c0, r0;
    if (b < 6192) {
        int bb = b - 2304;
        in = Wqkv; out = WqkvT; R = HID; C = N3;
        c0 = (bb % 108) * 32; r0 = (bb / 108) * 32;
    } else {
        int bb = b - 6192;
        in = Wproj; out = WprojT; R = HID; C = HID;
        c0 = (bb % 36) * 32; r0 = (bb / 36) * 32;
    }
    int tx = tid & 31, ty = tid >> 5;
#pragma unroll
    for (int i = 0; i < 4; ++i)
        tl[ty + 8*i][tx] = in[(size_t)(r0 + ty + 8*i) * C + c0 + tx];
    __syncthreads();
#pragma unroll
    for (int i = 0; i < 4; ++i)
        out[(size_t)(c0 + ty + 8*i) * R + r0 + tx] = (bf16)tl[tx][ty + 8*i];
}

// ---------------- fused QKV GEMM + RoPE + pack epilogue ----------------
// Tile 128(seq) x 144(=2 heads); 1152 % 144 == 0 so a tile never straddles the
// Q/K/V sections and every RoPE pair (d, d+-36) is inside the tile. BK=64 with
// source-baked XOR swizzle (rule 21). Epilogue: acc+bias -> bf16 LDS image
// [128][144] (aliases As/Bs), then cooperative RoPE + direct write to Qp /
// swizzled K-image / transposed V-image. qkv_b is never materialized.
__global__ __launch_bounds__(256)
void gemm_qkv(const bf16* __restrict__ A, const bf16* __restrict__ BT,
              const float* __restrict__ bias, const float* __restrict__ cs,
              const float* __restrict__ sn, bf16* __restrict__ Qp,
              bf16* __restrict__ KVp)
{
    __shared__ __align__(16) char smem[36864];   // As 16KB | Bs 18KB ; Ep 36KB (alias)
    bf16* Ep = (bf16*)smem;
    int tid = threadIdx.x;
    int lane = tid & 63, w = tid >> 6;
    int wgid = xcd_swz(blockIdx.x, gridDim.x);   // 768 blocks
    int m0 = (wgid & 31) * 128;
    int ntile = wgid >> 5;                        // 0..23
    int n0 = ntile * 144;
    int lq = lane & 15, lk = lane >> 4;

    int kx0 = ((lk ^ (lq & 7)) << 4);
    int kx1 = (((4 + lk) ^ (lq & 7)) << 4);

    f32x4 acc[2][9] = {};

    for (int k0 = 0; k0 < HID; k0 += 64) {
        __syncthreads();
#pragma unroll
        for (int j = 0; j < 9; ++j) {
            int c = j * 256 + tid;
            if (j < 4) {                                  // A: 1024 chunks
                int row = c >> 3, kc = c & 7;
                gload_lds16(A + (size_t)(m0 + row) * HID + k0 + ((kc ^ (row & 7)) << 3),
                            smem + c * 16);
            } else if (j < 8 || tid < 128) {              // B: 1152 chunks
                int c2 = c - 1024;
                int row = c2 >> 3, kc = c2 & 7;
                gload_lds16(BT + (size_t)(n0 + row) * HID + k0 + ((kc ^ (row & 7)) << 3),
                            smem + 16384 + c2 * 16);
            }
        }
        __syncthreads();
#pragma unroll
        for (int ks = 0; ks < 2; ++ks) {
            int kx = ks ? kx1 : kx0;
            bf16x8 af[2], bfr[9];
#pragma unroll
            for (int m = 0; m < 2; ++m)
                af[m] = *(const bf16x8*)(smem + (w * 32 + m * 16 + lq) * 128 + kx);
#pragma unroll
            for (int n = 0; n < 9; ++n)
                bfr[n] = *(const bf16x8*)(smem + 16384 + (n * 16 + lq) * 128 + kx);
#pragma unroll
            for (int m = 0; m < 2; ++m)
#pragma unroll
                for (int n = 0; n < 9; ++n)
                    acc[m][n] = __builtin_amdgcn_mfma_f32_16x16x32_bf16(af[m], bfr[n], acc[m][n], 0, 0, 0);
        }
    }

    // ---- epilogue phase 1: acc + bias -> bf16 LDS image [128][144] ----
    __syncthreads();
#pragma unroll
    for (int m = 0; m < 2; ++m)
#pragma unroll
        for (int n = 0; n < 9; ++n) {
            float bv = bias[n0 + n * 16 + lq];
#pragma unroll
            for (int r = 0; r < 4; ++r)
                Ep[(w * 32 + m * 16 + lk * 4 + r) * 144 + n * 16 + lq] =
                    (bf16)(acc[m][n][r] + bv);
        }
    __syncthreads();

    // ---- epilogue phase 2: RoPE + scatter into Qp / K-image / V-image ----
    int sec = n0 / HID;                 // 0 Q, 1 K, 2 V
    int h0 = (n0 - sec * HID) / HD;     // first head of the tile's 2
    for (int i = tid; i < 128 * 144; i += 256) {
        int row = i / 144, c = i % 144;
        int s = m0 + row;
        int hh = h0 + (c >= 72);
        int d = c - ((c >= 72) ? 72 : 0);
        float v = (float)Ep[row * 144 + c];
        int key = s & 63, t = s >> 6;
        if (sec == 2) {
            size_t base = ((size_t)(hh * 64 + t)) * TILE_ELEMS + 8192;
            KVp[base + d * 64 + (((key >> 3) ^ (d & 7)) << 3) + (key & 7)] = (bf16)v;
        } else {
            int dp  = (d < 36) ? d + 36 : d - 36;
            float sg = (d < 36) ? -1.f : 1.f;
            float v2 = (float)Ep[row * 144 + (c - d + dp)];
            float cv = cs[s * HD + d], sv = sn[s * HD + d];
            float ov = v * cv + sg * v2 * sv;
            if (sec == 0) {
                Qp[((size_t)hh * SEQ + s) * DQ + d] = (bf16)(ov * QSCALE);
            } else {
                size_t base = ((size_t)(hh * 64 + t)) * TILE_ELEMS;
                KVp[base + (key * 16 + ((d >> 3) ^ (key & 15))) * 8 + (d & 7)] = (bf16)ov;
            }
        }
    }
}

// ---------------- GEMM: C[M][N] = A[M][K] * BT[N][K]^T + bias (proj) ----------------
// BK=64, XOR swizzle kc^=(row&7) baked into the GLOBAL source (linear LDS dest).
template<int OUT_F32>
__global__ __launch_bounds__(256)
void gemm_bt(const bf16* __restrict__ A, const bf16* __restrict__ BT,
             const float* __restrict__ bias, void* __restrict__ out,
             int M, int N, int K)
{
    __shared__ __align__(16) bf16 As[128 * 64];
    __shared__ __align__(16) bf16 Bs[128 * 64];
    int tid = threadIdx.x;
    int lane = tid & 63, w = tid >> 6;
    int wm = w & 1, wn = w >> 1;
    int nwg  = gridDim.x * gridDim.y;
    int wgid = xcd_swz(blockIdx.y * gridDim.x + blockIdx.x, nwg);
    int m0 = (wgid % gridDim.x) * 128, n0 = (wgid / gridDim.x) * 128;
    int lq = lane & 15, lk = lane >> 4;

    int kx0 = ((lk ^ (lq & 7)) << 4);
    int kx1 = (((4 + lk) ^ (lq & 7)) << 4);

    f32x4 acc[4][4] = {};

    for (int k0 = 0; k0 < K; k0 += 64) {
        __syncthreads();
#pragma unroll
        for (int j = 0; j < 4; ++j) {
            int c = j * 256 + tid;
            int row = c >> 3, kc = c & 7;
            int koff = k0 + ((kc ^ (row & 7)) << 3);
            gload_lds16(A  + (size_t)(m0 + row) * K + koff, (char*)As + c * 16);
            gload_lds16(BT + (size_t)(n0 + row) * K + koff, (char*)Bs + c * 16);
        }
        __syncthreads();
#pragma unroll
        for (int ks = 0; ks < 2; ++ks) {
            int kx = ks ? kx1 : kx0;
            bf16x8 af[4], bfr[4];
#pragma unroll
            for (int m = 0; m < 4; ++m)
                af[m] = *(const bf16x8*)((char*)As + (wm * 64 + m * 16 + lq) * 128 + kx);
#pragma unroll
            for (int n = 0; n < 4; ++n)
                bfr[n] = *(const bf16x8*)((char*)Bs + (wn * 64 + n * 16 + lq) * 128 + kx);
#pragma unroll
            for (int m = 0; m < 4; ++m)
#pragma unroll
                for (int n = 0; n < 4; ++n)
                    acc[m][n] = __builtin_amdgcn_mfma_f32_16x16x32_bf16(af[m], bfr[n], acc[m][n], 0, 0, 0);
        }
    }

    int rb = m0 + wm * 64, cb = n0 + wn * 64;
#pragma unroll
    for (int m = 0; m < 4; ++m) {
#pragma unroll
        for (int n = 0; n < 4; ++n) {
            int col = cb + n * 16 + lq;
            float b = bias[col];
#pragma unroll
            for (int r = 0; r < 4; ++r) {
                int row = rb + m * 16 + lk * 4 + r;
                float v = acc[m][n][r] + b;
                if (OUT_F32) ((float*)out)[(size_t)row * N + col] = v;
                else         ((bf16*)out)[(size_t)row * N + col] = (bf16)v;
            }
        }
    }
}

// ---- flash attention: 8 waves x 32q, 3-buffer rotation, T15 within-wave pipeline ----
// (R13's attn_fwd11 verbatim -- the 103.3us operating point; R14's zip regressed.)
__global__ __launch_bounds__(512, 2)
void attn_fwd11(const bf16* __restrict__ Qp, const bf16* __restrict__ KVp,
                bf16* __restrict__ Oout)
{
    __shared__ __align__(16) char smem[86016];   // 3 x 28672

    const int o = blockIdx.x;
    const int x = o & 7, s = o >> 3;
    const int h  = x * 2 + (s >> 4);
    const int q0 = (s & 15) * QBLK;
    const int tid = threadIdx.x, lane = tid & 63, w = tid >> 6;
    const int ql = lane & 31, hi = lane >> 5;
    const int q  = q0 + w * 32 + ql;

    bf16x8 qf[5];
    const bf16* qbase = Qp + ((size_t)h * SEQ + q) * DQ + hi * 8;
#pragma unroll
    for (int ks = 0; ks < 5; ++ks) qf[ks] = *(const bf16x8*)(qbase + ks * 16);

    int aK[5], aV[4];
#pragma unroll
    for (int ks = 0; ks < 5; ++ks)
        aK[ks] = ql * 256 + (((ks * 2 + hi) ^ (ql & 15)) * 16);
#pragma unroll
    for (int u = 0; u < 4; ++u)
        aV[u] = 16384 + ql * 128 + (((u * 2 + hi) ^ (ql & 7)) * 16);

    f32x16 o_[3] = {};           // O^T accum; V row 72 (ones) carries l

    const bf16* kvbase = KVp + (size_t)h * (64 * TILE_ELEMS) + (size_t)tid * 8;

#define STAGE(T, DB) do {                                                      \
        const bf16* s_ = kvbase + (size_t)(T) * TILE_ELEMS;                    \
        char* d_ = smem + (DB) + tid * 16;                                     \
        _Pragma("unroll")                                                      \
        for (int j_ = 0; j_ < 3; ++j_)                                         \
            gload_lds16(s_ + j_ * 4096, d_ + j_ * 8192);                       \
        if (tid < 256) gload_lds16(s_ + 12288, d_ + 24576);                    \
    } while (0)

    auto qk = [&](const char* bK, f32x16& sa, f32x16& sb) {
        __builtin_amdgcn_s_setprio(1);
#pragma unroll
        for (int ks = 0; ks < 5; ++ks) {
            bf16x8 kf = *(const bf16x8*)(bK + aK[ks]);
            sa = __builtin_amdgcn_mfma_f32_32x32x16_bf16(kf, qf[ks], sa, 0, 0, 0);
        }
#pragma unroll
        for (int ks = 0; ks < 5; ++ks) {
            bf16x8 kf = *(const bf16x8*)(bK + 8192 + aK[ks]);
            sb = __builtin_amdgcn_mfma_f32_32x32x16_bf16(kf, qf[ks], sb, 0, 0, 0);
        }
        __builtin_amdgcn_s_setprio(0);
    };

    auto expv = [&](const f32x16& sa, const f32x16& sb, const char* bV) {
        uint32_t wd[16];
#pragma unroll
        for (int i = 0; i < 8; ++i) {
            wd[i]   = (uint32_t)bfbits(EXP2F(sa[2*i])) | ((uint32_t)bfbits(EXP2F(sa[2*i+1])) << 16);
            wd[8+i] = (uint32_t)bfbits(EXP2F(sb[2*i])) | ((uint32_t)bfbits(EXP2F(sb[2*i+1])) << 16);
        }
        PLSWAP(wd[0], wd[2]);   PLSWAP(wd[1], wd[3]);
        PLSWAP(wd[4], wd[6]);   PLSWAP(wd[5], wd[7]);
        PLSWAP(wd[8], wd[10]);  PLSWAP(wd[9], wd[11]);
        PLSWAP(wd[12], wd[14]); PLSWAP(wd[13], wd[15]);
        u32x4 u0 = {wd[0],wd[1],wd[2],wd[3]},   u1 = {wd[4],wd[5],wd[6],wd[7]};
        u32x4 u2 = {wd[8],wd[9],wd[10],wd[11]}, u3 = {wd[12],wd[13],wd[14],wd[15]};
        bf16x8 pb[4] = { __builtin_bit_cast(bf16x8, u0), __builtin_bit_cast(bf16x8, u1),
                         __builtin_bit_cast(bf16x8, u2), __builtin_bit_cast(bf16x8, u3) };
        __builtin_amdgcn_s_setprio(1);
#pragma unroll
        for (int db = 0; db < 3; ++db)
#pragma unroll
            for (int u = 0; u < 4; ++u) {
                bf16x8 vf = *(const bf16x8*)(bV + db * 4096 + aV[u]);
                o_[db] = __builtin_amdgcn_mfma_f32_32x32x16_bf16(vf, pb[u], o_[db], 0, 0, 0);
            }
        __builtin_amdgcn_s_setprio(0);
    };

    f32x16 pa = {}, pb_ = {};    // previous tile's scores (pipeline state)

    STAGE(0, 0);
    asm volatile("s_waitcnt vmcnt(0)" ::: "memory");
    __builtin_amdgcn_s_barrier();
    STAGE(1, 28672);
    qk(smem, pa, pb_);
    asm volatile("s_waitcnt vmcnt(0)" ::: "memory");
    __builtin_amdgcn_s_barrier();

#define BODY(T, KB, VB, SB) do {                                               \
        if ((T) < 63) STAGE((T) + 1, SB);                                      \
        f32x16 ca = {}, cb = {};                                               \
        qk(smem + (KB), ca, cb);                                               \
        expv(pa, pb_, smem + (VB));                                            \
        pa = ca; pb_ = cb;                                                     \
        __builtin_amdgcn_sched_barrier(0);                                     \
        asm volatile("s_waitcnt vmcnt(0)" ::: "memory");                       \
        __builtin_amdgcn_s_barrier();                                          \
    } while (0)

    for (int t = 1; t < 64; t += 3) {
        BODY(t,     28672, 0,     57344);
        BODY(t + 1, 57344, 28672, 0);
        BODY(t + 2, 0,     57344, 28672);
    }
    expv(pa, pb_, smem);         // drain: tile 63 (V resident in buffer 0)
#undef BODY
#undef STAGE

    // ---- epilogue: LDS transpose (stride 82 = 41 words, odd -> conflict-free) ----
    __syncthreads();
    bf16* Os = (bf16*)smem;                        // [QBLK][82]
    {
        float lv  = o_[2][4];                      // d=72 row holds l (hi=0 lanes)
        float lo_ = __shfl_xor(lv, 32);
        float invl = 1.0f / (hi ? lo_ : lv);
        int qloc = w * 32 + ql;
#pragma unroll
        for (int db = 0; db < 3; ++db)
#pragma unroll
            for (int r = 0; r < 16; ++r) {
                int dloc = (r & 3) + 8 * (r >> 2) + 4 * hi;
                int d = db * 32 + dloc;
                if (d < HD) Os[qloc * 82 + d] = (bf16)(o_[db][r] * invl);
            }
    }
    __syncthreads();
    for (int i = tid; i < QBLK * 36; i += 512) {
        int row = i / 36, c = i % 36;
        uint32_t val = *(const uint32_t*)((const char*)Os + row * 164 + c * 4);
        *(uint32_t*)((char*)Oout + (size_t)(q0 + row) * 2304 + h * 144 + c * 4) = val;
    }
}

extern "C" void kernel_launch(void* const* d_in, const int* in_sizes, int n_in,
                              void* d_out, int out_size, void* d_ws, size_t ws_size,
                              hipStream_t stream)
{
    const float* hidden = (const float*)d_in[0];
    // d_in[1] = cu_seqlens: unused by the reference
    const float* cosT  = (const float*)d_in[2];
    const float* sinT  = (const float*)d_in[3];
    const float* Wqkv  = (const float*)d_in[4];
    const float* bqkv  = (const float*)d_in[5];
    const float* Wproj = (const float*)d_in[6];
    const float* bproj = (const float*)d_in[7];

    char* ws = (char*)d_ws;
    size_t off = 0;
    auto alloc = [&](size_t bytes) {
        char* p = ws + off;
        off += (bytes + 255) & ~(size_t)255;
        return p;
    };
    bf16* hid_b  = (bf16*)alloc((size_t)SEQ * HID * 2);
    bf16* WqkvT  = (bf16*)alloc((size_t)N3  * HID * 2);
    bf16* WprojT = (bf16*)alloc((size_t)HID * HID * 2);
    bf16* Qp     = (bf16*)alloc((size_t)NH * SEQ * DQ * 2);
    bf16* KVp    = (bf16*)alloc((size_t)NH * 64 * TILE_ELEMS * 2);
    bf16* attno  = hid_b;  // overlay: hid_b dead after gemm_qkv

    prep<<<10304, 256, 0, stream>>>(hidden, Wqkv, Wproj, hid_b, WqkvT, WprojT, Qp, KVp);
    gemm_qkv<<<768, 256, 0, stream>>>(hid_b, WqkvT, bqkv, cosT, sinT, Qp, KVp);
    attn_fwd11<<<dim3(SEQ / QBLK * NH), 512, 0, stream>>>(Qp, KVp, attno);
    gemm_bt<1><<<dim3(SEQ / 128, HID / 128), 256, 0, stream>>>(attno, WprojT, bproj, d_out,
                                                               SEQ, HID, HID);
}

// Round 16
// 201.745 us; speedup vs baseline: 1.1933x; 1.1933x over previous
//
#include <hip/hip_runtime.h>
#include <hip/hip_bf16.h>
#include <stdint.h>

#define SEQ 4096
#define HID 1152
#define NH  16
#define HD  72
#define N3  3456
#define DQ  80      // Q padded head dim (5 x 16)
#define QBLK 256    // q rows per block (8 waves x 32)
#define TILE_ELEMS 14336  // 28KB tile image: K 64x256B = 16KB, V 96x128B = 12KB

typedef __bf16 bf16;
typedef __bf16 bf16x8 __attribute__((ext_vector_type(8)));
typedef float  f32x4  __attribute__((ext_vector_type(4)));
typedef float  f32x16 __attribute__((ext_vector_type(16)));
typedef uint32_t u32x4 __attribute__((ext_vector_type(4)));

#define EXP2F(x) __builtin_amdgcn_exp2f(x)
#define PLSWAP(a, b) asm("v_permlane32_swap_b32 %0, %1" : "+v"(a), "+v"(b))

__device__ __forceinline__ void gload_lds16(const void* g, void* l) {
    __builtin_amdgcn_global_load_lds(
        (__attribute__((address_space(1))) void*)(void*)g,
        (__attribute__((address_space(3))) void*)l, 16, 0, 0);
}
__device__ __forceinline__ uint16_t bfbits(float x) {
    return __builtin_bit_cast(uint16_t, (bf16)x);
}

// ---------------- fused prep: hidden f32->bf16 + both weight transposes ----------------
// blocks [0,2304): cvt hidden; [2304,6192): Wqkv^T; [6192,7488): Wproj^T
__global__ __launch_bounds__(256)
void prep(const float* __restrict__ hidden, const float* __restrict__ Wqkv,
          const float* __restrict__ Wproj, bf16* __restrict__ hid_b,
          bf16* __restrict__ WqkvT, bf16* __restrict__ WprojT)
{
    __shared__ float tl[32][33];
    int b = blockIdx.x, tid = threadIdx.x;
    if (b < 2304) {
        int i = b * 256 + tid;
        const float4* p = (const float4*)hidden + (size_t)i * 2;
        float4 a = p[0], c = p[1];
        bf16x8 o;
        o[0]=(bf16)a.x; o[1]=(bf16)a.y; o[2]=(bf16)a.z; o[3]=(bf16)a.w;
        o[4]=(bf16)c.x; o[5]=(bf16)c.y; o[6]=(bf16)c.z; o[7]=(bf16)c.w;
        ((bf16x8*)hid_b)[i] = o;
        return;
    }
    const float* in; bf16* out; int R, C, c0, r0;
    if (b < 6192) {
        int bb = b - 2304;
        in = Wqkv; out = WqkvT; R = HID; C = N3;
        c0 = (bb % 108) * 32; r0 = (bb / 108) * 32;
    } else {
        int bb = b - 6192;
        in = Wproj; out = WprojT; R = HID; C = HID;
        c0 = (bb % 36) * 32; r0 = (bb / 36) * 32;
    }
    int tx = tid & 31, ty = tid >> 5;
#pragma unroll
    for (int i = 0; i < 4; ++i)
        tl[ty + 8*i][tx] = in[(size_t)(r0 + ty + 8*i) * C + c0 + tx];
    __syncthreads();
#pragma unroll
    for (int i = 0; i < 4; ++i)
        out[(size_t)(c0 + ty + 8*i) * R + r0 + tx] = (bf16)tl[tx][ty + 8*i];
}

// ---------------- GEMM: C[M][N] = A[M][K] * BT[N][K]^T + bias ----------------
// BK=64, XOR swizzle kc^=(row&7) baked into the GLOBAL source (linear LDS dest);
// reads fold the same involution into a lane-constant -> ~2-way conflicts.
// Block mapping: each XCD owns an m-STRIPE (gridDim.x/8 m-tiles, A-panels stay
// L2-resident ~1.2MB) and walks n-major (B panels stream once) -- fixes the
// A-restream pathology diagnosed on gemm_qkv in R15 (90MB FETCH).
template<int OUT_F32>
__global__ __launch_bounds__(256)
void gemm_bt(const bf16* __restrict__ A, const bf16* __restrict__ BT,
             const float* __restrict__ bias, void* __restrict__ out,
             int M, int N, int K)
{
    __shared__ __align__(16) bf16 As[128 * 64];
    __shared__ __align__(16) bf16 Bs[128 * 64];
    int tid = threadIdx.x;
    int lane = tid & 63, w = tid >> 6;
    int wm = w & 1, wn = w >> 1;
    int orig = blockIdx.y * gridDim.x + blockIdx.x;
    int xcd = orig & 7, v = orig >> 3;
    int mpx = gridDim.x >> 3;                 // m-tiles per XCD
    int m0 = (xcd * mpx + (v % mpx)) * 128;
    int n0 = (v / mpx) * 128;
    int lq = lane & 15, lk = lane >> 4;

    int kx0 = ((lk ^ (lq & 7)) << 4);
    int kx1 = (((4 + lk) ^ (lq & 7)) << 4);

    f32x4 acc[4][4] = {};

    for (int k0 = 0; k0 < K; k0 += 64) {
        __syncthreads();
#pragma unroll
        for (int j = 0; j < 4; ++j) {
            int c = j * 256 + tid;              // chunk 0..1023 per operand
            int row = c >> 3, kc = c & 7;
            int koff = k0 + ((kc ^ (row & 7)) << 3);
            gload_lds16(A  + (size_t)(m0 + row) * K + koff, (char*)As + c * 16);
            gload_lds16(BT + (size_t)(n0 + row) * K + koff, (char*)Bs + c * 16);
        }
        __syncthreads();
#pragma unroll
        for (int ks = 0; ks < 2; ++ks) {
            int kx = ks ? kx1 : kx0;
            bf16x8 af[4], bfr[4];
#pragma unroll
            for (int m = 0; m < 4; ++m)
                af[m] = *(const bf16x8*)((char*)As + (wm * 64 + m * 16 + lq) * 128 + kx);
#pragma unroll
            for (int n = 0; n < 4; ++n)
                bfr[n] = *(const bf16x8*)((char*)Bs + (wn * 64 + n * 16 + lq) * 128 + kx);
#pragma unroll
            for (int m = 0; m < 4; ++m)
#pragma unroll
                for (int n = 0; n < 4; ++n)
                    acc[m][n] = __builtin_amdgcn_mfma_f32_16x16x32_bf16(af[m], bfr[n], acc[m][n], 0, 0, 0);
        }
    }

    int rb = m0 + wm * 64, cb = n0 + wn * 64;
#pragma unroll
    for (int m = 0; m < 4; ++m) {
#pragma unroll
        for (int n = 0; n < 4; ++n) {
            int col = cb + n * 16 + lq;
            float b = bias[col];
#pragma unroll
            for (int r = 0; r < 4; ++r) {
                int row = rb + m * 16 + lk * 4 + r;
                float v2 = acc[m][n][r] + b;
                if (OUT_F32) ((float*)out)[(size_t)row * N + col] = v2;
                else         ((bf16*)out)[(size_t)row * N + col] = (bf16)v2;
            }
        }
    }
}

// ---------------- fused pack: RoPE Q/K + V-transpose into KVp tile images ----------------
// blocks [0,32768): rope; [32768,33792): V pack.
// KVp[h][t][14336]: 0..8191 K image (chunk = key*16 + (dchunk^(key&15)));
// 8192..14335 V image (chunk d*8+cpos holds keys (cpos^(d&7))*8.. at dim d;
// d 0..71 data, 72 ones (l via MFMA), 73..95 zero).
__global__ __launch_bounds__(256)
void pack(const bf16* __restrict__ qkv, const float* __restrict__ cs,
          const float* __restrict__ sn, bf16* __restrict__ Qp,
          bf16* __restrict__ KVp)
{
    __shared__ __align__(16) bf16 tl[64][80];
    int b = blockIdx.x, tid = threadIdx.x;
    if (b < 32768) {
        int idx = b * 256 + tid;                 // NH*SEQ*128
        int dd = idx & 127;
        int s  = (idx >> 7) & (SEQ - 1);
        int h  = idx >> 19;
        float qv = 0.f, kv = 0.f;
        if (dd < HD) {
            const bf16* row = qkv + (size_t)s * N3 + h * HD;
            float c  = cs[s * HD + dd], si = sn[s * HD + dd];
            int   dp = (dd < 36) ? dd + 36 : dd - 36;
            float sg = (dd < 36) ? -1.f : 1.f;
            float qa = (float)row[dd],       qb = (float)row[dp];
            float ka = (float)row[HID + dd], kb = (float)row[HID + dp];
            qv = (qa * c + sg * qb * si) * (0.11785113019775793f * 1.4426950408889634f);
            kv =  ka * c + sg * kb * si;
        }
        int t = s >> 6, key = s & 63;
        int chunk = key * 16 + ((dd >> 3) ^ (key & 15));
        KVp[((size_t)(h * 64 + t)) * TILE_ELEMS + chunk * 8 + (dd & 7)] = (bf16)kv;
        if (dd < DQ) Qp[((size_t)h * SEQ + s) * DQ + dd] = (bf16)qv;
        return;
    }
    int bb = b - 32768;
    int t = bb & 63, h = bb >> 6, s0 = t * 64;
    for (int i = tid; i < 64 * 9; i += 256) {
        int key = i / 9, c8 = (i % 9) * 8;
        *(bf16x8*)&tl[key][c8] =
            *(const bf16x8*)&qkv[(size_t)(s0 + key) * N3 + 2 * HID + h * HD + c8];
    }
    __syncthreads();
    bf16* dst = KVp + ((size_t)(h * 64 + t)) * TILE_ELEMS + 8192;
    for (int vcid = tid; vcid < 768; vcid += 256) {     // 96 rows x 8 chunks
        int d = vcid >> 3, cpos = vcid & 7;
        int kb8 = (cpos ^ (d & 7)) << 3;
        bf16x8 v;
#pragma unroll
        for (int j = 0; j < 8; ++j)
            v[j] = (d < HD) ? tl[kb8 + j][d] : ((d == HD) ? (bf16)1.f : (bf16)0.f);
        *(bf16x8*)&dst[vcid * 8] = v;
    }
}

// ---- flash attention: 8 waves x 32q, 3-buffer rotation, T15 within-wave pipeline ----
// (R13's attn_fwd11 verbatim -- the 103.3us operating point.)
__global__ __launch_bounds__(512, 2)
void attn_fwd11(const bf16* __restrict__ Qp, const bf16* __restrict__ KVp,
                bf16* __restrict__ Oout)
{
    __shared__ __align__(16) char smem[86016];   // 3 x 28672

    const int o = blockIdx.x;
    const int x = o & 7, s = o >> 3;
    const int h  = x * 2 + (s >> 4);
    const int q0 = (s & 15) * QBLK;
    const int tid = threadIdx.x, lane = tid & 63, w = tid >> 6;
    const int ql = lane & 31, hi = lane >> 5;
    const int q  = q0 + w * 32 + ql;

    bf16x8 qf[5];
    const bf16* qbase = Qp + ((size_t)h * SEQ + q) * DQ + hi * 8;
#pragma unroll
    for (int ks = 0; ks < 5; ++ks) qf[ks] = *(const bf16x8*)(qbase + ks * 16);

    int aK[5], aV[4];
#pragma unroll
    for (int ks = 0; ks < 5; ++ks)
        aK[ks] = ql * 256 + (((ks * 2 + hi) ^ (ql & 15)) * 16);
#pragma unroll
    for (int u = 0; u < 4; ++u)
        aV[u] = 16384 + ql * 128 + (((u * 2 + hi) ^ (ql & 7)) * 16);

    f32x16 o_[3] = {};           // O^T accum; V row 72 (ones) carries l

    const bf16* kvbase = KVp + (size_t)h * (64 * TILE_ELEMS) + (size_t)tid * 8;

#define STAGE(T, DB) do {                                                      \
        const bf16* s_ = kvbase + (size_t)(T) * TILE_ELEMS;                    \
        char* d_ = smem + (DB) + tid * 16;                                     \
        _Pragma("unroll")                                                      \
        for (int j_ = 0; j_ < 3; ++j_)                                         \
            gload_lds16(s_ + j_ * 4096, d_ + j_ * 8192);                       \
        if (tid < 256) gload_lds16(s_ + 12288, d_ + 24576);                    \
    } while (0)

    auto qk = [&](const char* bK, f32x16& sa, f32x16& sb) {
        __builtin_amdgcn_s_setprio(1);
#pragma unroll
        for (int ks = 0; ks < 5; ++ks) {
            bf16x8 kf = *(const bf16x8*)(bK + aK[ks]);
            sa = __builtin_amdgcn_mfma_f32_32x32x16_bf16(kf, qf[ks], sa, 0, 0, 0);
        }
#pragma unroll
        for (int ks = 0; ks < 5; ++ks) {
            bf16x8 kf = *(const bf16x8*)(bK + 8192 + aK[ks]);
            sb = __builtin_amdgcn_mfma_f32_32x32x16_bf16(kf, qf[ks], sb, 0, 0, 0);
        }
        __builtin_amdgcn_s_setprio(0);
    };

    auto expv = [&](const f32x16& sa, const f32x16& sb, const char* bV) {
        uint32_t wd[16];
#pragma unroll
        for (int i = 0; i < 8; ++i) {
            wd[i]   = (uint32_t)bfbits(EXP2F(sa[2*i])) | ((uint32_t)bfbits(EXP2F(sa[2*i+1])) << 16);
            wd[8+i] = (uint32_t)bfbits(EXP2F(sb[2*i])) | ((uint32_t)bfbits(EXP2F(sb[2*i+1])) << 16);
        }
        PLSWAP(wd[0], wd[2]);   PLSWAP(wd[1], wd[3]);
        PLSWAP(wd[4], wd[6]);   PLSWAP(wd[5], wd[7]);
        PLSWAP(wd[8], wd[10]);  PLSWAP(wd[9], wd[11]);
        PLSWAP(wd[12], wd[14]); PLSWAP(wd[13], wd[15]);
        u32x4 u0 = {wd[0],wd[1],wd[2],wd[3]},   u1 = {wd[4],wd[5],wd[6],wd[7]};
        u32x4 u2 = {wd[8],wd[9],wd[10],wd[11]}, u3 = {wd[12],wd[13],wd[14],wd[15]};
        bf16x8 pb[4] = { __builtin_bit_cast(bf16x8, u0), __builtin_bit_cast(bf16x8, u1),
                         __builtin_bit_cast(bf16x8, u2), __builtin_bit_cast(bf16x8, u3) };
        __builtin_amdgcn_s_setprio(1);
#pragma unroll
        for (int db = 0; db < 3; ++db)
#pragma unroll
            for (int u = 0; u < 4; ++u) {
                bf16x8 vf = *(const bf16x8*)(bV + db * 4096 + aV[u]);
                o_[db] = __builtin_amdgcn_mfma_f32_32x32x16_bf16(vf, pb[u], o_[db], 0, 0, 0);
            }
        __builtin_amdgcn_s_setprio(0);
    };

    f32x16 pa = {}, pb_ = {};    // previous tile's scores (pipeline state)

    STAGE(0, 0);
    asm volatile("s_waitcnt vmcnt(0)" ::: "memory");
    __builtin_amdgcn_s_barrier();
    STAGE(1, 28672);
    qk(smem, pa, pb_);
    asm volatile("s_waitcnt vmcnt(0)" ::: "memory");
    __builtin_amdgcn_s_barrier();

#define BODY(T, KB, VB, SB) do {                                               \
        if ((T) < 63) STAGE((T) + 1, SB);                                      \
        f32x16 ca = {}, cb = {};                                               \
        qk(smem + (KB), ca, cb);                                               \
        expv(pa, pb_, smem + (VB));                                            \
        pa = ca; pb_ = cb;                                                     \
        __builtin_amdgcn_sched_barrier(0);                                     \
        asm volatile("s_waitcnt vmcnt(0)" ::: "memory");                       \
        __builtin_amdgcn_s_barrier();                                          \
    } while (0)

    for (int t = 1; t < 64; t += 3) {
        BODY(t,     28672, 0,     57344);
        BODY(t + 1, 57344, 28672, 0);
        BODY(t + 2, 0,     57344, 28672);
    }
    expv(pa, pb_, smem);         // drain: tile 63 (V resident in buffer 0)
#undef BODY
#undef STAGE

    // ---- epilogue: LDS transpose (stride 82 = 41 words, odd -> conflict-free) ----
    __syncthreads();
    bf16* Os = (bf16*)smem;                        // [QBLK][82]
    {
        float lv  = o_[2][4];                      // d=72 row holds l (hi=0 lanes)
        float lo_ = __shfl_xor(lv, 32);
        float invl = 1.0f / (hi ? lo_ : lv);
        int qloc = w * 32 + ql;
#pragma unroll
        for (int db = 0; db < 3; ++db)
#pragma unroll
            for (int r = 0; r < 16; ++r) {
                int dloc = (r & 3) + 8 * (r >> 2) + 4 * hi;
                int d = db * 32 + dloc;
                if (d < HD) Os[qloc * 82 + d] = (bf16)(o_[db][r] * invl);
            }
    }
    __syncthreads();
    for (int i = tid; i < QBLK * 36; i += 512) {
        int row = i / 36, c = i % 36;
        uint32_t val = *(const uint32_t*)((const char*)Os + row * 164 + c * 4);
        *(uint32_t*)((char*)Oout + (size_t)(q0 + row) * 2304 + h * 144 + c * 4) = val;
    }
}

extern "C" void kernel_launch(void* const* d_in, const int* in_sizes, int n_in,
                              void* d_out, int out_size, void* d_ws, size_t ws_size,
                              hipStream_t stream)
{
    const float* hidden = (const float*)d_in[0];
    // d_in[1] = cu_seqlens: unused by the reference
    const float* cosT  = (const float*)d_in[2];
    const float* sinT  = (const float*)d_in[3];
    const float* Wqkv  = (const float*)d_in[4];
    const float* bqkv  = (const float*)d_in[5];
    const float* Wproj = (const float*)d_in[6];
    const float* bproj = (const float*)d_in[7];

    char* ws = (char*)d_ws;
    size_t off = 0;
    auto alloc = [&](size_t bytes) {
        char* p = ws + off;
        off += (bytes + 255) & ~(size_t)255;
        return p;
    };
    bf16* hid_b  = (bf16*)alloc((size_t)SEQ * HID * 2);
    bf16* WqkvT  = (bf16*)alloc((size_t)N3  * HID * 2);
    bf16* WprojT = (bf16*)alloc((size_t)HID * HID * 2);
    bf16* qkv_b  = (bf16*)alloc((size_t)SEQ * N3  * 2);
    bf16* Qp     = (bf16*)alloc((size_t)NH * SEQ * DQ * 2);
    bf16* KVp    = (bf16*)alloc((size_t)NH * 64 * TILE_ELEMS * 2);
    bf16* attno  = hid_b;  // overlay: hid_b dead after GEMM1

    prep<<<7488, 256, 0, stream>>>(hidden, Wqkv, Wproj, hid_b, WqkvT, WprojT);
    gemm_bt<0><<<dim3(SEQ / 128, N3 / 128), 256, 0, stream>>>(hid_b, WqkvT, bqkv, qkv_b,
                                                              SEQ, N3, HID);
    pack<<<33792, 256, 0, stream>>>(qkv_b, cosT, sinT, Qp, KVp);
    attn_fwd11<<<dim3(SEQ / QBLK * NH), 512, 0, stream>>>(Qp, KVp, attno);
    gemm_bt<1><<<dim3(SEQ / 128, HID / 128), 256, 0, stream>>>(attno, WprojT, bproj, d_out,
                                                               SEQ, HID, HID);
}

// Round 18
// 197.833 us; speedup vs baseline: 1.2169x; 1.0198x over previous
//
#include <hip/hip_runtime.h>
#include <hip/hip_bf16.h>
#include <stdint.h>

#define SEQ 4096
#define HID 1152
#define NH  16
#define HD  72
#define N3  3456
#define DQ  80        // Q padded head dim (5 x 16)
#define QBLK 256      // q rows per block (8 waves x 32)
#define TILE_B 19584  // tile image bytes: K 64x160B = 10240, V 73x128B = 9344
#define TILE_E 9792   // tile elems
#define VBASE 10240   // V image byte offset within tile
#define ZOFF  58752   // static 16B zero block (after 3 buffers)

typedef __bf16 bf16;
typedef __bf16 bf16x8 __attribute__((ext_vector_type(8)));
typedef float  f32x4  __attribute__((ext_vector_type(4)));
typedef float  f32x16 __attribute__((ext_vector_type(16)));
typedef uint32_t u32x4 __attribute__((ext_vector_type(4)));

#define EXP2F(x) __builtin_amdgcn_exp2f(x)
#define PLSWAP(a, b) asm("v_permlane32_swap_b32 %0, %1" : "+v"(a), "+v"(b))

__device__ __forceinline__ void gload_lds16(const void* g, void* l) {
    __builtin_amdgcn_global_load_lds(
        (__attribute__((address_space(1))) void*)(void*)g,
        (__attribute__((address_space(3))) void*)l, 16, 0, 0);
}
__device__ __forceinline__ uint16_t bfbits(float x) {
    return __builtin_bit_cast(uint16_t, (bf16)x);
}

// ---------------- fused prep: hidden f32->bf16 + both weight transposes ----------------
__global__ __launch_bounds__(256)
void prep(const float* __restrict__ hidden, const float* __restrict__ Wqkv,
          const float* __restrict__ Wproj, bf16* __restrict__ hid_b,
          bf16* __restrict__ WqkvT, bf16* __restrict__ WprojT)
{
    __shared__ float tl[32][33];
    int b = blockIdx.x, tid = threadIdx.x;
    if (b < 2304) {
        int i = b * 256 + tid;
        const float4* p = (const float4*)hidden + (size_t)i * 2;
        float4 a = p[0], c = p[1];
        bf16x8 o;
        o[0]=(bf16)a.x; o[1]=(bf16)a.y; o[2]=(bf16)a.z; o[3]=(bf16)a.w;
        o[4]=(bf16)c.x; o[5]=(bf16)c.y; o[6]=(bf16)c.z; o[7]=(bf16)c.w;
        ((bf16x8*)hid_b)[i] = o;
        return;
    }
    const float* in; bf16* out; int R, C, c0, r0;
    if (b < 6192) {
        int bb = b - 2304;
        in = Wqkv; out = WqkvT; R = HID; C = N3;
        c0 = (bb % 108) * 32; r0 = (bb / 108) * 32;
    } else {
        int bb = b - 6192;
        in = Wproj; out = WprojT; R = HID; C = HID;
        c0 = (bb % 36) * 32; r0 = (bb / 36) * 32;
    }
    int tx = tid & 31, ty = tid >> 5;
#pragma unroll
    for (int i = 0; i < 4; ++i)
        tl[ty + 8*i][tx] = in[(size_t)(r0 + ty + 8*i) * C + c0 + tx];
    __syncthreads();
#pragma unroll
    for (int i = 0; i < 4; ++i)
        out[(size_t)(c0 + ty + 8*i) * R + r0 + tx] = (bf16)tl[tx][ty + 8*i];
}

// ---------------- GEMM: C[M][N] = A[M][K] * BT[N][K]^T + bias ----------------
// BK=64, source-baked XOR swizzle; m-stripe-per-XCD mapping (R16 win).
template<int OUT_F32>
__global__ __launch_bounds__(256)
void gemm_bt(const bf16* __restrict__ A, const bf16* __restrict__ BT,
             const float* __restrict__ bias, void* __restrict__ out,
             int M, int N, int K)
{
    __shared__ __align__(16) bf16 As[128 * 64];
    __shared__ __align__(16) bf16 Bs[128 * 64];
    int tid = threadIdx.x;
    int lane = tid & 63, w = tid >> 6;
    int wm = w & 1, wn = w >> 1;
    int orig = blockIdx.y * gridDim.x + blockIdx.x;
    int xcd = orig & 7, v = orig >> 3;
    int mpx = gridDim.x >> 3;
    int m0 = (xcd * mpx + (v % mpx)) * 128;
    int n0 = (v / mpx) * 128;
    int lq = lane & 15, lk = lane >> 4;

    int kx0 = ((lk ^ (lq & 7)) << 4);
    int kx1 = (((4 + lk) ^ (lq & 7)) << 4);

    f32x4 acc[4][4] = {};

    for (int k0 = 0; k0 < K; k0 += 64) {
        __syncthreads();
#pragma unroll
        for (int j = 0; j < 4; ++j) {
            int c = j * 256 + tid;
            int row = c >> 3, kc = c & 7;
            int koff = k0 + ((kc ^ (row & 7)) << 3);
            gload_lds16(A  + (size_t)(m0 + row) * K + koff, (char*)As + c * 16);
            gload_lds16(BT + (size_t)(n0 + row) * K + koff, (char*)Bs + c * 16);
        }
        __syncthreads();
#pragma unroll
        for (int ks = 0; ks < 2; ++ks) {
            int kx = ks ? kx1 : kx0;
            bf16x8 af[4], bfr[4];
#pragma unroll
            for (int m = 0; m < 4; ++m)
                af[m] = *(const bf16x8*)((char*)As + (wm * 64 + m * 16 + lq) * 128 + kx);
#pragma unroll
            for (int n = 0; n < 4; ++n)
                bfr[n] = *(const bf16x8*)((char*)Bs + (wn * 64 + n * 16 + lq) * 128 + kx);
#pragma unroll
            for (int m = 0; m < 4; ++m)
#pragma unroll
                for (int n = 0; n < 4; ++n)
                    acc[m][n] = __builtin_amdgcn_mfma_f32_16x16x32_bf16(af[m], bfr[n], acc[m][n], 0, 0, 0);
        }
    }

    int rb = m0 + wm * 64, cb = n0 + wn * 64;
#pragma unroll
    for (int m = 0; m < 4; ++m) {
#pragma unroll
        for (int n = 0; n < 4; ++n) {
            int col = cb + n * 16 + lq;
            float b = bias[col];
#pragma unroll
            for (int r = 0; r < 4; ++r) {
                int row = rb + m * 16 + lk * 4 + r;
                float v2 = acc[m][n][r] + b;
                if (OUT_F32) ((float*)out)[(size_t)row * N + col] = v2;
                else         ((bf16*)out)[(size_t)row * N + col] = (bf16)v2;
            }
        }
    }
}

// ---------------- fused pack: RoPE Q/K + V-transpose into trimmed KVp tiles ----------------
// blocks [0,20480): rope over NH*SEQ*80; [20480,21504): V pack.
// KVp[h][t][9792]: elems 0..5119 = K image, 64 keys x 80 elems (160B rows),
// K chunk at pos = dchunk<8 ? dchunk^(key&7) : dchunk (dchunk 0..9).
// elems 5120..9791 = V image, 73 rows x 128B (d 0..71 data, 72 = ones for l);
// chunk at storage pos cpos holds keys (cpos^(d&7))*8..
__global__ __launch_bounds__(256)
void pack(const bf16* __restrict__ qkv, const float* __restrict__ cs,
          const float* __restrict__ sn, bf16* __restrict__ Qp,
          bf16* __restrict__ KVp)
{
    __shared__ __align__(16) bf16 tl[64][80];
    int b = blockIdx.x, tid = threadIdx.x;
    if (b < 20480) {
        int idx = b * 256 + tid;                 // NH*SEQ*80
        int dd = idx % 80;
        int rest = idx / 80;
        int s = rest & (SEQ - 1), h = rest >> 12;
        float qv = 0.f, kv = 0.f;
        if (dd < HD) {
            const bf16* row = qkv + (size_t)s * N3 + h * HD;
            float c  = cs[s * HD + dd], si = sn[s * HD + dd];
            int   dp = (dd < 36) ? dd + 36 : dd - 36;
            float sg = (dd < 36) ? -1.f : 1.f;
            float qa = (float)row[dd],       qb = (float)row[dp];
            float ka = (float)row[HID + dd], kb = (float)row[HID + dp];
            qv = (qa * c + sg * qb * si) * (0.11785113019775793f * 1.4426950408889634f);
            kv =  ka * c + sg * kb * si;
        }
        int t = s >> 6, key = s & 63;
        int dchunk = dd >> 3;
        int pos = (dchunk < 8) ? (dchunk ^ (key & 7)) : dchunk;
        // K row = 80 ELEMENTS (160 bytes) -- R17 bug was key*160 here.
        KVp[((size_t)(h * 64 + t)) * TILE_E + key * 80 + pos * 8 + (dd & 7)] = (bf16)kv;
        Qp[((size_t)h * SEQ + s) * DQ + dd] = (bf16)qv;
        return;
    }
    int bb = b - 20480;
    int t = bb & 63, h = bb >> 6, s0 = t * 64;
    for (int i = tid; i < 64 * 9; i += 256) {
        int key = i / 9, c8 = (i % 9) * 8;
        *(bf16x8*)&tl[key][c8] =
            *(const bf16x8*)&qkv[(size_t)(s0 + key) * N3 + 2 * HID + h * HD + c8];
    }
    __syncthreads();
    bf16* dst = KVp + ((size_t)(h * 64 + t)) * TILE_E + 5120;
    for (int vcid = tid; vcid < 584; vcid += 256) {     // 73 rows x 8 chunks
        int d = vcid >> 3, cpos = vcid & 7;
        int kb8 = (cpos ^ (d & 7)) << 3;
        bf16x8 v;
#pragma unroll
        for (int j = 0; j < 8; ++j)
            v[j] = (d < HD) ? tl[kb8 + j][d] : (bf16)1.f;   // d==72: ones row
        *(bf16x8*)&dst[vcid * 8] = v;
    }
}

// ---- flash attention: 8 waves x 32q, 3-buffer rotation (trimmed 19.6KB tiles) ----
// R13 body; K rows 160B span-8 swizzle; V 73 rows + static-zero redirect for
// PV db=2 pad lanes (ql>8). No-max softmax; l via ones-row of V.
__global__ __launch_bounds__(512, 2)
void attn_fwd13(const bf16* __restrict__ Qp, const bf16* __restrict__ KVp,
                bf16* __restrict__ Oout)
{
    __shared__ __align__(16) char smem[59392];   // 3 x 19584 + zero block

    const int o = blockIdx.x;
    const int x = o & 7, s = o >> 3;
    const int h  = x * 2 + (s >> 4);
    const int q0 = (s & 15) * QBLK;
    const int tid = threadIdx.x, lane = tid & 63, w = tid >> 6;
    const int ql = lane & 31, hi = lane >> 5;
    const int q  = q0 + w * 32 + ql;

    bf16x8 qf[5];
    const bf16* qbase = Qp + ((size_t)h * SEQ + q) * DQ + hi * 8;
#pragma unroll
    for (int ks = 0; ks < 5; ++ks) qf[ks] = *(const bf16x8*)(qbase + ks * 16);

    // K read offsets: row ql (keys 0..31), 160B rows, span-8 swizzle; ks=4 fixed
    int aK[5];
#pragma unroll
    for (int ks = 0; ks < 4; ++ks)
        aK[ks] = ql * 160 + (((ks * 2 + hi) ^ (ql & 7)) * 16);
    aK[4] = ql * 160 + (8 + hi) * 16;
    // V read offsets (rows = db*32+ql within 73-row image at VBASE)
    int aV[4];
#pragma unroll
    for (int u = 0; u < 4; ++u)
        aV[u] = VBASE + ql * 128 + (((u * 2 + hi) ^ (ql & 7)) * 16);

    f32x16 o_[3] = {};           // O^T accum; V row 72 (ones) carries l

    const bf16* kvh = KVp + (size_t)h * (64 * TILE_E);

#define STAGE(T, DB) do {                                                      \
        const bf16* s_ = kvh + (size_t)(T) * TILE_E;                           \
        _Pragma("unroll")                                                      \
        for (int j_ = 0; j_ < 3; ++j_) {                                       \
            int c_ = j_ * 512 + tid;                                           \
            if (c_ < 1224) gload_lds16(s_ + c_ * 8, smem + (DB) + c_ * 16);    \
        }                                                                      \
    } while (0)

    auto qk = [&](const char* bK, f32x16& sa, f32x16& sb) {
        __builtin_amdgcn_s_setprio(1);
#pragma unroll
        for (int ks = 0; ks < 5; ++ks) {
            bf16x8 kf = *(const bf16x8*)(bK + aK[ks]);
            sa = __builtin_amdgcn_mfma_f32_32x32x16_bf16(kf, qf[ks], sa, 0, 0, 0);
        }
#pragma unroll
        for (int ks = 0; ks < 5; ++ks) {
            bf16x8 kf = *(const bf16x8*)(bK + 5120 + aK[ks]);   // keys 32..63
            sb = __builtin_amdgcn_mfma_f32_32x32x16_bf16(kf, qf[ks], sb, 0, 0, 0);
        }
        __builtin_amdgcn_s_setprio(0);
    };

    auto expv = [&](const f32x16& sa, const f32x16& sb, const char* bV) {
        uint32_t wd[16];
#pragma unroll
        for (int i = 0; i < 8; ++i) {
            wd[i]   = (uint32_t)bfbits(EXP2F(sa[2*i])) | ((uint32_t)bfbits(EXP2F(sa[2*i+1])) << 16);
            wd[8+i] = (uint32_t)bfbits(EXP2F(sb[2*i])) | ((uint32_t)bfbits(EXP2F(sb[2*i+1])) << 16);
        }
        PLSWAP(wd[0], wd[2]);   PLSWAP(wd[1], wd[3]);
        PLSWAP(wd[4], wd[6]);   PLSWAP(wd[5], wd[7]);
        PLSWAP(wd[8], wd[10]);  PLSWAP(wd[9], wd[11]);
        PLSWAP(wd[12], wd[14]); PLSWAP(wd[13], wd[15]);
        u32x4 u0 = {wd[0],wd[1],wd[2],wd[3]},   u1 = {wd[4],wd[5],wd[6],wd[7]};
        u32x4 u2 = {wd[8],wd[9],wd[10],wd[11]}, u3 = {wd[12],wd[13],wd[14],wd[15]};
        bf16x8 pb[4] = { __builtin_bit_cast(bf16x8, u0), __builtin_bit_cast(bf16x8, u1),
                         __builtin_bit_cast(bf16x8, u2), __builtin_bit_cast(bf16x8, u3) };
        __builtin_amdgcn_s_setprio(1);
#pragma unroll
        for (int db = 0; db < 3; ++db)
#pragma unroll
            for (int u = 0; u < 4; ++u) {
                const char* pv;
                if (db < 2)          pv = bV + db * 4096 + aV[u];
                else if (ql <= 8)    pv = bV + 8192 + aV[u];      // rows 64..72
                else                 pv = smem + ZOFF;            // zero pad rows
                bf16x8 vf = *(const bf16x8*)pv;
                o_[db] = __builtin_amdgcn_mfma_f32_32x32x16_bf16(vf, pb[u], o_[db], 0, 0, 0);
            }
        __builtin_amdgcn_s_setprio(0);
    };

    f32x16 pa = {}, pb_ = {};    // previous tile's scores (pipeline state)

    // zero block init + prologue
    if (tid < 4) ((float*)(smem + ZOFF))[tid] = 0.f;
    STAGE(0, 0);
    asm volatile("s_waitcnt vmcnt(0) lgkmcnt(0)" ::: "memory");
    __builtin_amdgcn_s_barrier();
    STAGE(1, TILE_B);
    qk(smem, pa, pb_);
    asm volatile("s_waitcnt vmcnt(0)" ::: "memory");
    __builtin_amdgcn_s_barrier();

#define BODY(T, KB, VB, SB) do {                                               \
        if ((T) < 63) STAGE((T) + 1, SB);                                      \
        f32x16 ca = {}, cb = {};                                               \
        qk(smem + (KB), ca, cb);                                               \
        expv(pa, pb_, smem + (VB));                                            \
        pa = ca; pb_ = cb;                                                     \
        __builtin_amdgcn_sched_barrier(0);                                     \
        asm volatile("s_waitcnt vmcnt(0)" ::: "memory");                       \
        __builtin_amdgcn_s_barrier();                                          \
    } while (0)

    for (int t = 1; t < 64; t += 3) {
        BODY(t,     TILE_B,     0,          2 * TILE_B);
        BODY(t + 1, 2 * TILE_B, TILE_B,     0);
        BODY(t + 2, 0,          2 * TILE_B, TILE_B);
    }
    expv(pa, pb_, smem);         // drain: tile 63 (V resident in buffer 0)
#undef BODY
#undef STAGE

    // ---- epilogue: LDS transpose (stride 82 = 41 words, odd -> conflict-free) ----
    __syncthreads();
    bf16* Os = (bf16*)smem;                        // [QBLK][82]
    {
        float lv  = o_[2][4];                      // d=72 row holds l (hi=0 lanes)
        float lo_ = __shfl_xor(lv, 32);
        float invl = 1.0f / (hi ? lo_ : lv);
        int qloc = w * 32 + ql;
#pragma unroll
        for (int db = 0; db < 3; ++db)
#pragma unroll
            for (int r = 0; r < 16; ++r) {
                int dloc = (r & 3) + 8 * (r >> 2) + 4 * hi;
                int d = db * 32 + dloc;
                if (d < HD) Os[qloc * 82 + d] = (bf16)(o_[db][r] * invl);
            }
    }
    __syncthreads();
    for (int i = tid; i < QBLK * 36; i += 512) {
        int row = i / 36, c = i % 36;
        uint32_t val = *(const uint32_t*)((const char*)Os + row * 164 + c * 4);
        *(uint32_t*)((char*)Oout + (size_t)(q0 + row) * 2304 + h * 144 + c * 4) = val;
    }
}

extern "C" void kernel_launch(void* const* d_in, const int* in_sizes, int n_in,
                              void* d_out, int out_size, void* d_ws, size_t ws_size,
                              hipStream_t stream)
{
    const float* hidden = (const float*)d_in[0];
    // d_in[1] = cu_seqlens: unused by the reference
    const float* cosT  = (const float*)d_in[2];
    const float* sinT  = (const float*)d_in[3];
    const float* Wqkv  = (const float*)d_in[4];
    const float* bqkv  = (const float*)d_in[5];
    const float* Wproj = (const float*)d_in[6];
    const float* bproj = (const float*)d_in[7];

    char* ws = (char*)d_ws;
    size_t off = 0;
    auto alloc = [&](size_t bytes) {
        char* p = ws + off;
        off += (bytes + 255) & ~(size_t)255;
        return p;
    };
    bf16* hid_b  = (bf16*)alloc((size_t)SEQ * HID * 2);
    bf16* WqkvT  = (bf16*)alloc((size_t)N3  * HID * 2);
    bf16* WprojT = (bf16*)alloc((size_t)HID * HID * 2);
    bf16* qkv_b  = (bf16*)alloc((size_t)SEQ * N3  * 2);
    bf16* Qp     = (bf16*)alloc((size_t)NH * SEQ * DQ * 2);
    bf16* KVp    = (bf16*)alloc((size_t)NH * 64 * TILE_E * 2);
    bf16* attno  = hid_b;  // overlay: hid_b dead after GEMM1

    prep<<<7488, 256, 0, stream>>>(hidden, Wqkv, Wproj, hid_b, WqkvT, WprojT);
    gemm_bt<0><<<dim3(SEQ / 128, N3 / 128), 256, 0, stream>>>(hid_b, WqkvT, bqkv, qkv_b,
                                                              SEQ, N3, HID);
    pack<<<21504, 256, 0, stream>>>(qkv_b, cosT, sinT, Qp, KVp);
    attn_fwd13<<<dim3(SEQ / QBLK * NH), 512, 0, stream>>>(Qp, KVp, attno);
    gemm_bt<1><<<dim3(SEQ / 128, HID / 128), 256, 0, stream>>>(attno, WprojT, bproj, d_out,
                                                               SEQ, HID, HID);
}